// Round 1
// 339.715 us; speedup vs baseline: 1.0357x; 1.0357x over previous
//
#include <hip/hip_runtime.h>
#include <hip/hip_fp16.h>

#define XDIM 256
#define YDIM 256
#define ZDIM 32
#define NT 384
#define NA 180
#define AG 4                      // angles per block
#define SW 265                    // half2 cells per staged row (odd dword stride -> bank decorrelation)
#define SROWS 136                 // staged rows per strip: y0 in [128*st-4, 128*st+132)
#define SLICE_CELLS (SROWS * SW)  // 36040
#define SLICE_BYTES (SLICE_CELLS * 4)  // 144160
#define PSUM_BYTES (1024 * 8)
#define SMEM_BYTES (SLICE_BYTES + PSUM_BYTES)  // 152352 <= 163840

// Block: one z-PAIR x 4 angles, looping over 2 y-strips of 128 rows.
// LDS cell (y,x) holds half2(vol[z0], vol[z1]) so one set of ray geometry
// feeds a packed-f16 x-lerp producing both z outputs; y-lerp stays f32.
// 4-cell zero pad on all sides absorbs the +-2-sample interval widening
// (clamps deleted: out-of-volume taps read exact zeros == reference's
// zero-weight semantics). Strip ownership of each sample is decided by a
// shared integer boundary ib so the two strips partition [glo,ghi) exactly.
__global__ __launch_bounds__(1024) void proj_kernel(
    const float* __restrict__ vol, const float* __restrict__ phis,
    float* __restrict__ out) {
  extern __shared__ char smem[];
  __half2* sl = reinterpret_cast<__half2*>(smem);
  unsigned int* slu = reinterpret_cast<unsigned int*>(smem);
  float2* psum = reinterpret_cast<float2*>(smem + SLICE_BYTES);

  const int tid = threadIdx.x;
  const int zp = blockIdx.x;   // 0..15 z-pair
  const int ag = blockIdx.y;   // 0..44 angle group
  const int col = tid & 255;
  const int q = tid >> 8;      // t-quarter (it % 4 == q)
  const float u = (float)col - 127.5f;

  float c_[AG], s_[AG], bx_[AG], by_[AG];
  int lo_[2][AG], hi_[2][AG];

#pragma unroll
  for (int j = 0; j < AG; ++j) {
    const float phi = phis[ag * AG + j] * 0.017453292519943295f;
    const float c = cosf(phi), s = sinf(phi);
    const float bx = fmaf(u, -s, 127.5f);
    const float by = fmaf(u, c, 127.5f);
    c_[j] = c; s_[j] = s; bx_[j] = bx; by_[j] = by;
    // global t-interval (widened +-2; every executed sample exact via pads)
    float lo = 0.f, hi = (float)NT;
    if (fabsf(c) < 1e-6f) {
      if (bx <= -1.f || bx >= 256.f) { lo = 1.f; hi = 0.f; }
    } else {
      float t1 = (-1.f - bx) / c + 191.5f;
      float t2 = (256.f - bx) / c + 191.5f;
      lo = fmaxf(lo, fminf(t1, t2) - 2.f);
      hi = fminf(hi, fmaxf(t1, t2) + 2.f);
    }
    if (fabsf(s) < 1e-6f) {
      if (by <= -1.f || by >= 256.f) { lo = 1.f; hi = 0.f; }
    } else {
      float t1 = (-1.f - by) / s + 191.5f;
      float t2 = (256.f - by) / s + 191.5f;
      lo = fmaxf(lo, fminf(t1, t2) - 2.f);
      hi = fminf(hi, fmaxf(t1, t2) + 2.f);
    }
    const int glo = (int)fmaxf(lo, 0.f);
    const int ghi = (int)fminf(hi, (float)NT);
    // exact partition at y == 128 via shared integer boundary ib
    int l0, h0, l1, h1;
    if (fabsf(s) < 1e-6f) {
      if (by < 128.f) { l0 = glo; h0 = ghi; l1 = 1; h1 = 0; }
      else            { l0 = 1; h0 = 0; l1 = glo; h1 = ghi; }
    } else {
      float fb = (128.f - by) / s + 191.5f;
      fb = fminf(fmaxf(fb, -2.f), 400.f);
      const int ib = (int)ceilf(fb);
      if (s > 0.f) { l0 = glo; h0 = min(ghi, ib); l1 = max(glo, ib); h1 = ghi; }
      else         { l0 = max(glo, ib); h0 = ghi; l1 = glo; h1 = min(ghi, ib); }
    }
    lo_[0][j] = l0; hi_[0][j] = h0; lo_[1][j] = l1; hi_[1][j] = h1;
  }

  float2 acc[AG];
#pragma unroll
  for (int j = 0; j < AG; ++j) acc[j] = make_float2(0.f, 0.f);

  const float* vsrc0 = vol + (zp * 2) * (YDIM * XDIM);
  const float* vsrc1 = vsrc0 + YDIM * XDIM;

#pragma unroll
  for (int st = 0; st < 2; ++st) {
    __syncthreads();  // previous strip's reads done before overwrite
    // ---- zero pad rows (4 rows: global y -4..-1 for st=0, 256..259 for st=1)
    {
      const int padrow = st ? 132 : 0;
      for (int k = tid; k < 4 * SW; k += 1024) {
        int r = k / SW;
        int x = k - r * SW;
        slu[(padrow + r) * SW + x] = 0u;
      }
      // zero pad cols (lx 0..3 and 260..264, all staged rows)
      for (int k = tid; k < SROWS * 9; k += 1024) {
        int r = k / 9;
        int cc = k - r * 9;
        int lx = (cc < 4) ? cc : 256 + cc;
        slu[r * SW + lx] = 0u;
      }
    }
    // ---- fill interior: 132 rows x 256 cols == 33*1024 cells exactly
    {
      const int gr0 = st ? 124 : 0;  // first global row staged with data
      const int lr0 = st ? 0 : 4;    // its local row
      const float* p0 = vsrc0 + gr0 * XDIM;
      const float* p1 = vsrc1 + gr0 * XDIM;
#pragma unroll
      for (int i = 0; i < 33; ++i) {
        int k = tid + i * 1024;
        int r = k >> 8;
        int x = k & 255;
        sl[(lr0 + r) * SW + x + 4] = __floats2half2_rn(p0[k], p1[k]);
      }
    }
    __syncthreads();

    // cell index offset: lr = y0 + 4 - 128*st, lx = x0 + 4
    const int K = (4 - 128 * st) * SW + 4;
#pragma unroll
    for (int j = 0; j < AG; ++j) {
      const int lo = lo_[st][j], hi = hi_[st][j];
      const int start = lo + ((q - lo) & 3);
      float t = (float)start - 191.5f;   // half-integers: t += 4 exact in fp32
      const float tend = (float)hi - 191.5f;
      const float c = c_[j], s = s_[j], bx = bx_[j], by = by_[j];
      float a0 = acc[j].x, a1 = acc[j].y;
#pragma unroll 2
      for (; t < tend; t += 4.f) {
        float x = fmaf(t, c, bx);
        float y = fmaf(t, s, by);
        float x0f = floorf(x), y0f = floorf(y);
        float fx = x - x0f, fy = y - y0f;
        // exact: |y0*265 + x0| < 2^24
        int ai = (int)fmaf(y0f, (float)SW, x0f) + K;
        const __half2* p = sl + ai;
        __half2 d00 = p[0], d01 = p[1], d10 = p[SW], d11 = p[SW + 1];
        __half2 fx2 = __float2half2_rn(fx);
        __half2 hx0 = __hfma2(__hsub2(d01, d00), fx2, d00);  // x-lerp, both z
        __half2 hx1 = __hfma2(__hsub2(d11, d10), fx2, d10);
        float omfy = 1.f - fy;
        a0 = fmaf(__low2float(hx0), omfy, a0);
        a0 = fmaf(__low2float(hx1), fy, a0);
        a1 = fmaf(__high2float(hx0), omfy, a1);
        a1 = fmaf(__high2float(hx1), fy, a1);
      }
      acc[j].x = a0; acc[j].y = a1;
    }
  }

  // ---- reduce 4 t-quarters and write both z outputs per angle
#pragma unroll
  for (int j = 0; j < AG; ++j) {
    __syncthreads();
    psum[tid] = acc[j];
    __syncthreads();
    if (tid < 256) {
      float2 pa = psum[col], pb = psum[256 + col], pc = psum[512 + col],
             pd = psum[768 + col];
      const int a = ag * AG + j;
      out[(a * ZDIM + zp * 2) * XDIM + col] = pa.x + pb.x + pc.x + pd.x;
      out[(a * ZDIM + zp * 2 + 1) * XDIM + col] = pa.y + pb.y + pc.y + pd.y;
    }
  }
}

extern "C" void kernel_launch(void* const* d_in, const int* in_sizes, int n_in,
                              void* d_out, int out_size, void* d_ws, size_t ws_size,
                              hipStream_t stream) {
  const float* vol = (const float*)d_in[0];
  const float* phis = (const float*)d_in[1];
  float* out = (float*)d_out;
  (void)hipFuncSetAttribute((const void*)proj_kernel,
                            hipFuncAttributeMaxDynamicSharedMemorySize,
                            SMEM_BYTES);
  dim3 grid(ZDIM / 2, NA / AG);
  proj_kernel<<<grid, 1024, SMEM_BYTES, stream>>>(vol, phis, out);
}